// Round 20
// baseline (352.584 us; speedup 1.0000x reference)
//
#include <hip/hip_runtime.h>
#include <math.h>

#define NPOS 1024   // H*W
#define DH   32     // dim head
#define NBH  8      // B * HEADS
#define CH   256
#define INNER 128   // HEADS*DIM_HEAD
#define NWG  512    // grid size == 2 WG/CU x 256 CU (co-residency exact)

typedef __attribute__((ext_vector_type(4))) _Float16 half4;
typedef __attribute__((ext_vector_type(4))) float f32x4;

// Canonical CDNA 16x16x16 f16 MFMA.  A: row=l&15, k=4*(l>>4)+j.  B: col=l&15,
// same k ordering.  C/D: col=l&15, row=(l>>4)*4+reg.  (HW-verified R9-R19.)
#define MFMA16(a, b, c) __builtin_amdgcn_mfma_f32_16x16x16f16((a), (b), (c), 0, 0, 0)

// Fragment-tiled f16 layout (R18, passing):
//   idx(bh, t, db, lg, lr, j) = ((((bh*64 + t)*2 + db)*4 + lg)*16 + lr)*4 + j

union h2u { _Float16 h; unsigned short u; };

__device__ __forceinline__ unsigned short f2h(float f) {
  h2u c; c.h = (_Float16)f; return c.u;
}
__device__ __forceinline__ float h2f(unsigned short u) {
  h2u c; c.u = u; return (float)c.h;
}
__device__ __forceinline__ half4 ldh4(const unsigned short* __restrict__ p) {
  union { half4 v; uint2 u; } r;
  r.u = *(const uint2*)p;
  return r.v;
}
__device__ __forceinline__ void split4(const float* v, half4& hi, half4& lo) {
  unsigned short h[4], lw[4];
  #pragma unroll
  for (int j = 0; j < 4; ++j) {
    h[j]  = f2h(v[j]);
    lw[j] = f2h(v[j] - h2f(h[j]));
  }
  union { half4 v4; unsigned int u[2]; } H, L;
  H.u[0] = (unsigned int)h[0]  | ((unsigned int)h[1]  << 16);
  H.u[1] = (unsigned int)h[2]  | ((unsigned int)h[3]  << 16);
  L.u[0] = (unsigned int)lw[0] | ((unsigned int)lw[1] << 16);
  L.u[1] = (unsigned int)lw[2] | ((unsigned int)lw[3] << 16);
  hi = H.v4;  lo = L.v4;
}

// Device-scope grid barrier: count-up-to-NWG (slots zeroed per call by host
// memset).  All NWG WGs are co-resident by construction (launch_bounds(512,4)
// -> 2 WG/CU x 256 CU = NWG), so arrive-and-spin cannot deadlock.
__device__ __forceinline__ void grid_barrier(unsigned* slot) {
  __syncthreads();
  __threadfence();                     // release: make phase stores visible (agent scope)
  if (threadIdx.x == 0) {
    atomicAdd(slot, 1u);               // device-scope RMW
    while (__hip_atomic_load(slot, __ATOMIC_RELAXED, __HIP_MEMORY_SCOPE_AGENT) < NWG)
      __builtin_amdgcn_s_sleep(16);
  }
  __syncthreads();
  __threadfence();                     // acquire: invalidate caches before reads
}

// ---------------------------------------------------------------------------
// Single fused kernel: 512 WGs x 512 threads, 3 phases, 2 grid barriers.
// Phase bodies are verbatim R19 (passing): proj MFMA GEMM -> attn -> outproj.
// ---------------------------------------------------------------------------
__global__ __launch_bounds__(512, 4) void fused_all(
    const float* __restrict__ x,  const float* __restrict__ Wq,
    const float* __restrict__ Wk, const float* __restrict__ Wv,
    const float* __restrict__ Wo,
    const float* __restrict__ bwp, const float* __restrict__ swp,
    const float* __restrict__ ssp, float* __restrict__ out,
    unsigned short* __restrict__ Qhi, unsigned short* __restrict__ Qlo,
    unsigned short* __restrict__ Khi, unsigned short* __restrict__ Klo,
    unsigned short* __restrict__ Vthi, unsigned short* __restrict__ Vtlo,
    float* __restrict__ Onorm, unsigned* bar)
{
  __shared__ __align__(16) char smem[19664];   // max over phases

  const int bid = blockIdx.x;
  const int tid = threadIdx.x;
  const int l   = tid & 63;
  const int wid = __builtin_amdgcn_readfirstlane(tid >> 6); // 0..7 SGPR
  const int lr  = l & 15;
  const int lg  = l >> 4;

  // ================= phase 1: QKV projection (R19 body) ===================
  {
    float (*part)[3][12][64] = (float(*)[3][12][64])smem;   // 18432 B
    const int jl = wid >> 2;         // job within WG (0..1)
    const int kq = wid & 3;          // K quarter (0..3)

    const int job   = bid * 2 + jl;  // 0..1023
    const int b     = job >> 9;
    const int itile = (job >> 6) & 7;
    const int ntile = job & 63;

    const int i_row = itile * 16 + lr;
    const int gn    = ntile * 16 + lr;

    const float* xb  = x + (size_t)b * CH * NPOS;
    const float* wqr = Wq + (size_t)i_row * CH;
    const float* wkr = Wk + (size_t)i_row * CH;
    const float* wvr = Wv + (size_t)i_row * CH;

    f32x4 aq = {0.f,0.f,0.f,0.f}, ak = {0.f,0.f,0.f,0.f}, av = {0.f,0.f,0.f,0.f};

    #pragma unroll
    for (int kk = 0; kk < 4; ++kk) {
      const int cb = kq * 64 + kk * 16 + lg * 4;

      float xv[4];
      #pragma unroll
      for (int j = 0; j < 4; ++j) xv[j] = xb[(size_t)(cb + j) * NPOS + gn];
      half4 Bhi, Blo;
      split4(xv, Bhi, Blo);

      {
        float4 wv4 = *(const float4*)(wqr + cb);
        float wv[4] = {wv4.x, wv4.y, wv4.z, wv4.w};
        half4 Ahi, Alo;  split4(wv, Ahi, Alo);
        aq = MFMA16(Ahi, Bhi, aq);
        aq = MFMA16(Ahi, Blo, aq);
        aq = MFMA16(Alo, Bhi, aq);
      }
      {
        float4 wv4 = *(const float4*)(wkr + cb);
        float wv[4] = {wv4.x, wv4.y, wv4.z, wv4.w};
        half4 Ahi, Alo;  split4(wv, Ahi, Alo);
        ak = MFMA16(Ahi, Bhi, ak);
        ak = MFMA16(Ahi, Blo, ak);
        ak = MFMA16(Alo, Bhi, ak);
      }
      {
        float4 wv4 = *(const float4*)(wvr + cb);
        float wv[4] = {wv4.x, wv4.y, wv4.z, wv4.w};
        half4 Ahi, Alo;  split4(wv, Ahi, Alo);
        av = MFMA16(Ahi, Bhi, av);
        av = MFMA16(Ahi, Blo, av);
        av = MFMA16(Alo, Bhi, av);
      }
    }

    if (kq > 0) {
      #pragma unroll
      for (int r = 0; r < 4; ++r) {
        part[jl][kq - 1][r][l]     = aq[r];
        part[jl][kq - 1][4 + r][l] = ak[r];
        part[jl][kq - 1][8 + r][l] = av[r];
      }
    }
    __syncthreads();
    if (kq == 0) {
      #pragma unroll
      for (int p = 0; p < 3; ++p)
        #pragma unroll
        for (int r = 0; r < 4; ++r) {
          aq[r] += part[jl][p][r][l];
          ak[r] += part[jl][p][4 + r][l];
          av[r] += part[jl][p][8 + r][l];
        }

      const float qs = 0.17677669529663687f;  // 1/sqrt(32)
      const int h  = itile >> 1;
      const int bh = b * 4 + h;
      const int db = itile & 1;

      unsigned short qh[4], ql[4], kh[4], kl[4], vh[4], vl[4];
      #pragma unroll
      for (int r = 0; r < 4; ++r) {
        float q = aq[r] * qs;
        qh[r] = f2h(q);   ql[r] = f2h(q - h2f(qh[r]));
        kh[r] = f2h(ak[r]); kl[r] = f2h(ak[r] - h2f(kh[r]));
        vh[r] = f2h(av[r]); vl[r] = f2h(av[r] - h2f(vh[r]));
      }

      const size_t qkb = ((((size_t)bh * 64 + ntile) * 2 + db) * 4 + lg) * 64
                       + (size_t)lr * 4;
      *(uint2*)(Qhi + qkb) = make_uint2((unsigned)qh[0] | ((unsigned)qh[1] << 16),
                                        (unsigned)qh[2] | ((unsigned)qh[3] << 16));
      *(uint2*)(Qlo + qkb) = make_uint2((unsigned)ql[0] | ((unsigned)ql[1] << 16),
                                        (unsigned)ql[2] | ((unsigned)ql[3] << 16));
      *(uint2*)(Khi + qkb) = make_uint2((unsigned)kh[0] | ((unsigned)kh[1] << 16),
                                        (unsigned)kh[2] | ((unsigned)kh[3] << 16));
      *(uint2*)(Klo + qkb) = make_uint2((unsigned)kl[0] | ((unsigned)kl[1] << 16),
                                        (unsigned)kl[2] | ((unsigned)kl[3] << 16));

      #pragma unroll
      for (int r = 0; r < 4; ++r) {
        const size_t vb = ((((size_t)bh * 64 + ntile) * 2 + db) * 4 + (lr >> 2)) * 64
                        + (size_t)(lg * 4 + r) * 4 + (lr & 3);
        Vthi[vb] = vh[r];
        Vtlo[vb] = vl[r];
      }
    }
  }

  grid_barrier(bar + 0);

  // ================= phase 2: fused attention (R19 body) ==================
  {
    float (*DlO)[32][17] = (float(*)[32][17])smem;            // 17408 B
    float (*DlS)[4][17]  = (float(*)[4][17])(smem + 17408);   // 2176 B
    float (*tabL)[4]     = (float(*)[4])(smem + 19584);       // 80 B

    const int w   = wid;
    const int bh  = bid & 7;         // == XCD
    const int q0  = (bid >> 3) * 16;
    const int fo  = lg * 64 + lr * 4;

    const float sc = ssp[0];
    const float bw = bwp[0];

    if (tid < 20) {
      const int cell = tid >> 2, p = tid & 3;
      float C[8];
      #pragma unroll
      for (int j = 0; j < 8; ++j) C[j] = swp[j] * sc;
      float maxc = 0.f;
      #pragma unroll
      for (int j = 0; j < 8; ++j) maxc = fmaxf(maxc, fabsf(C[j]));
      const float Bnd = fabsf(bw) * 6.0f + maxc;
      float a;
      if      (p == 0) a = (C[cell] + 4.f * C[cell+1] + C[cell+2]) * (1.f / 6.f) - Bnd;
      else if (p == 1) a = (-3.f * C[cell] + 3.f * C[cell+2]) * (1.f / 6.f);
      else if (p == 2) a = (3.f * C[cell] - 6.f * C[cell+1] + 3.f * C[cell+2]) * (1.f / 6.f);
      else             a = (-C[cell] + 3.f * C[cell+1] - 3.f * C[cell+2] + C[cell+3]) * (1.f / 6.f);
      tabL[cell][p] = a;
    }
    __syncthreads();

    const size_t qtb = ((size_t)bh * 64 + (q0 >> 4)) * 512;
    const half4 Bq_h0 = ldh4(Qhi + qtb + fo);
    const half4 Bq_h1 = ldh4(Qhi + qtb + 256 + fo);
    const half4 Bq_l0 = ldh4(Qlo + qtb + fo);
    const half4 Bq_l1 = ldh4(Qlo + qtb + 256 + fo);

    f32x4 accO0 = {0.f, 0.f, 0.f, 0.f};
    f32x4 accO1 = {0.f, 0.f, 0.f, 0.f};
    float ssum = 0.f;

    #pragma unroll 2
    for (int t = 0; t < 8; ++t) {
      const int kt  = w * 8 + t;
      const size_t ktb = ((size_t)bh * 64 + kt) * 512;

      const half4 Ak_h0 = ldh4(Khi + ktb + fo);
      const half4 Ak_h1 = ldh4(Khi + ktb + 256 + fo);
      const half4 Ak_l0 = ldh4(Klo + ktb + fo);
      const half4 Ak_l1 = ldh4(Klo + ktb + 256 + fo);

      f32x4 acc = {0.f, 0.f, 0.f, 0.f};
      acc = MFMA16(Ak_h0, Bq_h0, acc);
      acc = MFMA16(Ak_h1, Bq_h1, acc);
      acc = MFMA16(Ak_h0, Bq_l0, acc);
      acc = MFMA16(Ak_h1, Bq_l1, acc);
      acc = MFMA16(Ak_l0, Bq_h0, acc);
      acc = MFMA16(Ak_l1, Bq_h1, acc);

      unsigned short ph[4];
      #pragma unroll
      for (int r = 0; r < 4; ++r) {
        float s = acc[r];
        s = fminf(fmaxf(s, -6.0f), 6.0f);
        float e   = __expf(-s);
        float sil = s * __builtin_amdgcn_rcpf(1.0f + e);
        float tt  = fmaf(s, (1.0f / 2.4f), 2.5f);
        float cf  = fminf(floorf(tt), 4.0f);
        float u   = tt - cf;
        const float4 cv = *(const float4*)tabL[(int)cf];
        float spl = fmaf(fmaf(fmaf(cv.w, u, cv.z), u, cv.y), u, cv.x);
        float kan = fmaf(bw, sil, spl);
        unsigned short pu = f2h(__expf(kan));
        ph[r] = pu;
        ssum += h2f(pu);
      }
      union { half4 v; unsigned int u[2]; } Pb;
      Pb.u[0] = (unsigned int)ph[0] | ((unsigned int)ph[1] << 16);
      Pb.u[1] = (unsigned int)ph[2] | ((unsigned int)ph[3] << 16);

      const half4 Av_h0 = ldh4(Vthi + ktb + fo);
      const half4 Av_l0 = ldh4(Vtlo + ktb + fo);
      const half4 Av_h1 = ldh4(Vthi + ktb + 256 + fo);
      const half4 Av_l1 = ldh4(Vtlo + ktb + 256 + fo);
      accO0 = MFMA16(Av_h0, Pb.v, accO0);
      accO0 = MFMA16(Av_l0, Pb.v, accO0);
      accO1 = MFMA16(Av_h1, Pb.v, accO1);
      accO1 = MFMA16(Av_l1, Pb.v, accO1);
    }

    #pragma unroll
    for (int r = 0; r < 4; ++r) {
      DlO[w][4 * lg + r][lr]      = accO0[r];
      DlO[w][16 + 4 * lg + r][lr] = accO1[r];
    }
    DlS[w][lg][lr] = ssum;
    __syncthreads();

    {
      const int q = tid & 15;
      const int d = tid >> 4;     // 0..31 (512 threads)
      float o = 0.f, sden = 0.f;
      #pragma unroll
      for (int ww = 0; ww < 8; ++ww) {
        o += DlO[ww][d][q];
        #pragma unroll
        for (int g = 0; g < 4; ++g) sden += DlS[ww][g][q];
      }
      Onorm[((size_t)bh * DH + d) * NPOS + q0 + q] = o / sden;
    }
  }

  grid_barrier(bar + 1);

  // ================= phase 3: output projection (R19 math, 4 jobs/WG) =====
  {
    float (*part)[4][64] = (float(*)[4][64])smem;   // 4096 B
    const int jl = wid >> 1;         // job within WG (0..3)
    const int kh = wid & 1;          // K half (0..1), 64 i each

    const int job   = bid * 4 + jl;  // 0..2047
    const int b     = job >> 10;
    const int ctile = (job >> 6) & 15;
    const int ntile = job & 63;

    const int c_row = ctile * 16 + lr;
    const int gn    = ntile * 16 + lr;

    const float* ob = Onorm + (size_t)b * INNER * NPOS;
    const float* wr = Wo + (size_t)c_row * INNER;

    f32x4 acc = {0.f, 0.f, 0.f, 0.f};

    #pragma unroll
    for (int kk = 0; kk < 4; ++kk) {
      const int ib = kh * 64 + kk * 16 + lg * 4;

      float xv[4];
      #pragma unroll
      for (int j = 0; j < 4; ++j) xv[j] = ob[(size_t)(ib + j) * NPOS + gn];
      half4 Bhi, Blo;
      split4(xv, Bhi, Blo);

      float4 wv4 = *(const float4*)(wr + ib);
      float wv[4] = {wv4.x, wv4.y, wv4.z, wv4.w};
      half4 Ahi, Alo;
      split4(wv, Ahi, Alo);

      acc = MFMA16(Ahi, Bhi, acc);
      acc = MFMA16(Ahi, Blo, acc);
      acc = MFMA16(Alo, Bhi, acc);
    }

    if (kh == 1) {
      #pragma unroll
      for (int r = 0; r < 4; ++r) part[jl][r][l] = acc[r];
    }
    __syncthreads();
    if (kh == 0) {
      #pragma unroll
      for (int r = 0; r < 4; ++r) acc[r] += part[jl][r][l];
      #pragma unroll
      for (int r = 0; r < 4; ++r) {
        const int c = ctile * 16 + lg * 4 + r;
        out[((size_t)(b * CH + c)) * NPOS + gn] = acc[r];
      }
    }
  }
}

// ---------------------------------------------------------------------------
extern "C" void kernel_launch(void* const* d_in, const int* in_sizes, int n_in,
                              void* d_out, int out_size, void* d_ws, size_t ws_size,
                              hipStream_t stream)
{
  const float* x  = (const float*)d_in[0];
  const float* Wq = (const float*)d_in[1];
  const float* Wk = (const float*)d_in[2];
  const float* Wv = (const float*)d_in[3];
  const float* Wo = (const float*)d_in[4];
  const float* bw = (const float*)d_in[5];
  const float* sw = (const float*)d_in[6];
  const float* ss = (const float*)d_in[7];
  float* out = (float*)d_out;

  // workspace: Onorm (f32, 1MB) | 6x f16 QKV (512KB each) | barrier slots
  float* Onorm = (float*)d_ws;
  unsigned short* base = (unsigned short*)(Onorm + (size_t)NBH * DH * NPOS);
  const size_t QKN = (size_t)NBH * NPOS * DH;   // 262144 elements
  unsigned short* Qhi  = base;
  unsigned short* Qlo  = Qhi  + QKN;
  unsigned short* Khi  = Qlo  + QKN;
  unsigned short* Klo  = Khi  + QKN;
  unsigned short* Vthi = Klo  + QKN;
  unsigned short* Vtlo = Vthi + QKN;
  unsigned* bar = (unsigned*)(Vtlo + QKN);      // 2 x 4B barrier slots

  hipMemsetAsync(bar, 0, 2 * sizeof(unsigned), stream);
  fused_all<<<dim3(NWG), 512, 0, stream>>>(
      x, Wq, Wk, Wv, Wo, bw, sw, ss, out,
      Qhi, Qlo, Khi, Klo, Vthi, Vtlo, Onorm, bar);
}